// Round 3
// baseline (366.302 us; speedup 1.0000x reference)
//
#include <hip/hip_runtime.h>
#include <hip/hip_bf16.h>

#define B_ 16
#define I_ 256
#define O_ 256
#define T_ 512
#define L_ 8192
#define K_ 7
#define PAD_ 3
#define BN 64
#define NTILE 128            // L_/BN
#define LDK 264              // Xs row stride in bf16 (256 + 8 pad); 528 B = 33*16 keeps uint4 aligned

typedef unsigned short u16;
typedef unsigned int u32;
typedef __attribute__((ext_vector_type(8))) short short8;
typedef __attribute__((ext_vector_type(4))) float f32x4;

__device__ inline u16 f2bf(float f) {
    union { float f; u32 u; } v; v.f = f;
    u32 r = v.u + 0x7FFF + ((v.u >> 16) & 1);   // RNE
    return (u16)(r >> 16);
}

// ---------------- Kernel 1: mod[b][i] = t[b,:] . mod_w[i,:] + mod_b[i] ----------------
__global__ void mod_kernel(const float* __restrict__ t, const float* __restrict__ mod_w,
                           const float* __restrict__ mod_b, float* __restrict__ mod) {
    int g = blockIdx.x, b = blockIdx.y;
    int lane = threadIdx.x & 63, wv = threadIdx.x >> 6;
    const float* tb = t + b * T_;
    #pragma unroll
    for (int q = 0; q < 4; ++q) {
        int i = g * 16 + wv * 4 + q;
        const float* wr = mod_w + (size_t)i * T_;
        float s = 0.f;
        #pragma unroll
        for (int u = 0; u < 8; ++u) s += wr[lane + u * 64] * tb[lane + u * 64];
        #pragma unroll
        for (int d = 32; d; d >>= 1) s += __shfl_down(s, d);
        if (lane == 0) mod[b * I_ + i] = s + mod_b[i];
    }
}

// ---------------- Kernel 2: Wb[b][o][i] = bf16( proj_w[o,i]*(mod[b,i]+1) * demod[b,o] ) ----
__global__ void wmod_kernel(const float* __restrict__ proj_w, const float* __restrict__ mod,
                            u16* __restrict__ Wb) {
    int og = blockIdx.x, b = blockIdx.y;
    int lane = threadIdx.x & 63, wv = threadIdx.x >> 6;
    const float* mrow = mod + b * I_;
    #pragma unroll
    for (int q = 0; q < 4; ++q) {
        int o = og * 16 + wv * 4 + q;
        const float* pw = proj_w + (size_t)o * I_;
        float4 pv = *(const float4*)(pw + lane * 4);
        float4 mv = *(const float4*)(mrow + lane * 4);
        float v0 = pv.x * (mv.x + 1.f);
        float v1 = pv.y * (mv.y + 1.f);
        float v2 = pv.z * (mv.z + 1.f);
        float v3 = pv.w * (mv.w + 1.f);
        float ss = v0*v0 + v1*v1 + v2*v2 + v3*v3;
        #pragma unroll
        for (int d = 32; d; d >>= 1) ss += __shfl_xor(ss, d);
        float dem = rsqrtf(ss + 1e-8f);
        u32 lo = (u32)f2bf(v0 * dem) | ((u32)f2bf(v1 * dem) << 16);
        u32 hi = (u32)f2bf(v2 * dem) | ((u32)f2bf(v3 * dem) << 16);
        *(uint2*)(Wb + (size_t)(b * O_ + o) * I_ + lane * 4) = make_uint2(lo, hi);
    }
}

// ---------------- Kernel 3a: depthwise conv -> bf16 transposed tiles ----------------
// xt[b][tile][n][k]: n = col within 64-wide tile, k = channel (contiguous) — MFMA B-frag layout.
__global__ __launch_bounds__(256) void conv_kernel(
    const float* __restrict__ bx, const float* __restrict__ conv_w, u16* __restrict__ xt)
{
    __shared__ __align__(16) u16 Xs[BN * LDK];

    const int tile = blockIdx.x;
    const int b = blockIdx.y;
    const int l0 = tile * BN;
    const int tid = threadIdx.x;

    const int rq = tid >> 2;        // 0..63 -> i0 = 4*rq
    const int lq = tid & 3;
    const int i0 = rq * 4;
    const float* bxr = bx + (size_t)b * I_ * L_;
    const bool interior = (l0 >= 4) && (l0 + 72 <= L_);

    float wr[4][K_];
    #pragma unroll
    for (int di = 0; di < 4; ++di)
        #pragma unroll
        for (int j = 0; j < K_; ++j)
            wr[di][j] = conv_w[(i0 + di) * K_ + j];

    #pragma unroll
    for (int it = 0; it < 4; ++it) {
        const int lb = it * 16 + lq * 4;
        u16 hv[4][4];
        #pragma unroll
        for (int di = 0; di < 4; ++di) {
            const float* row = bxr + (size_t)(i0 + di) * L_ + l0;
            float x[12];
            if (interior) {
                const float4* rp = (const float4*)(row + lb - 4);
                float4 w0 = rp[0], w1 = rp[1], w2 = rp[2];
                x[0]=w0.x; x[1]=w0.y; x[2]=w0.z; x[3]=w0.w;
                x[4]=w1.x; x[5]=w1.y; x[6]=w1.z; x[7]=w1.w;
                x[8]=w2.x; x[9]=w2.y; x[10]=w2.z; x[11]=w2.w;
            } else {
                #pragma unroll
                for (int w = 0; w < 12; ++w) {
                    int p = l0 + lb - 4 + w;
                    x[w] = (p >= 0 && p < L_) ? row[lb - 4 + w] : 0.f;
                }
            }
            #pragma unroll
            for (int dl = 0; dl < 4; ++dl) {
                float a = 0.f;
                #pragma unroll
                for (int j = 0; j < K_; ++j) a += wr[di][j] * x[dl + 1 + j];
                hv[dl][di] = f2bf(a);
            }
        }
        #pragma unroll
        for (int dl = 0; dl < 4; ++dl) {
            int n = lb + dl;
            u32 lo = (u32)hv[dl][0] | ((u32)hv[dl][1] << 16);
            u32 hi = (u32)hv[dl][2] | ((u32)hv[dl][3] << 16);
            *(uint2*)(&Xs[n * LDK + i0]) = make_uint2(lo, hi);
        }
    }
    __syncthreads();

    // coalesced dump: 2048 16B-chunks, 8 per thread, dense [64][256]
    u16* dst = xt + (size_t)(b * NTILE + tile) * (BN * I_);
    #pragma unroll
    for (int r = 0; r < 8; ++r) {
        int g = tid + r * 256;
        int n = g >> 5;
        int c = g & 31;
        uint4 v = *(const uint4*)(&Xs[n * LDK + c * 8]);
        *(uint4*)(dst + (size_t)g * 8) = v;
    }
}

// ---------------- Kernel 3b: batched GEMM, no LDS, no barriers ----------------
// C(256x64) = W(256x256) * X(256x64) per (b, tile); frags loaded straight from global.
__global__ __launch_bounds__(256) void gemm_kernel(
    const u16* __restrict__ xt, const u16* __restrict__ Wb,
    const float* __restrict__ proj_b, float* __restrict__ out)
{
    const int tile = blockIdx.x;
    const int b = blockIdx.y;
    const int l0 = tile * BN;
    const int lane = threadIdx.x & 63;
    const int wv = threadIdx.x >> 6;
    const int mlane = lane & 15;
    const int quad = lane >> 4;

    f32x4 acc[4][4];
    #pragma unroll
    for (int r = 0; r < 4; ++r)
        #pragma unroll
        for (int c = 0; c < 4; ++c)
            acc[r][c] = (f32x4){0.f, 0.f, 0.f, 0.f};

    const u16* Wrow  = Wb + (size_t)(b * O_ + wv * 64 + mlane) * I_;
    const u16* Xtile = xt + (size_t)(b * NTILE + tile) * (BN * I_);

    for (int kb = 0; kb < 8; ++kb) {
        const int koff = kb * 32 + quad * 8;
        short8 a[4], bbf[4];
        #pragma unroll
        for (int r = 0; r < 4; ++r)
            a[r] = *(const short8*)(Wrow + r * 16 * I_ + koff);
        #pragma unroll
        for (int c = 0; c < 4; ++c)
            bbf[c] = *(const short8*)(Xtile + (c * 16 + mlane) * I_ + koff);
        #pragma unroll
        for (int r = 0; r < 4; ++r)
            #pragma unroll
            for (int c = 0; c < 4; ++c)
                acc[r][c] = __builtin_amdgcn_mfma_f32_16x16x32_bf16(a[r], bbf[c], acc[r][c], 0, 0, 0);
    }

    float* outb = out + (size_t)b * O_ * L_;
    #pragma unroll
    for (int r = 0; r < 4; ++r) {
        const int obase = wv * 64 + r * 16 + quad * 4;
        #pragma unroll
        for (int p = 0; p < 4; ++p) {
            const int o = obase + p;
            const float bias = proj_b[o];
            float* orow = outb + (size_t)o * L_ + l0 + mlane;
            #pragma unroll
            for (int c = 0; c < 4; ++c)
                orow[c * 16] = acc[r][c][p] + bias;
        }
    }
}

// ---------------- Fallback: round-1 fused kernel (used if ws too small) ----------------
__global__ __launch_bounds__(256) void main_kernel(
    const float* __restrict__ bx, const float* __restrict__ conv_w,
    const u16* __restrict__ Wb, const float* __restrict__ proj_b,
    float* __restrict__ out)
{
    __shared__ __align__(16) u16 Xs[BN * LDK];

    const int tile = blockIdx.x;
    const int b = blockIdx.y;
    const int l0 = tile * BN;
    const int tid = threadIdx.x;
    const int lane = tid & 63;
    const int wv = tid >> 6;
    const int mlane = lane & 15;
    const int quad = lane >> 4;

    const int rq = tid >> 2;
    const int lq = tid & 3;
    const int i0 = rq * 4;
    const float* bxr = bx + (size_t)b * I_ * L_;
    const bool interior = (l0 >= 4) && (l0 + 72 <= L_);

    float wr[4][K_];
    #pragma unroll
    for (int di = 0; di < 4; ++di)
        #pragma unroll
        for (int j = 0; j < K_; ++j)
            wr[di][j] = conv_w[(i0 + di) * K_ + j];

    for (int it = 0; it < 4; ++it) {
        const int lb = it * 16 + lq * 4;
        u16 hv[4][4];
        #pragma unroll
        for (int di = 0; di < 4; ++di) {
            const float* row = bxr + (size_t)(i0 + di) * L_ + l0;
            float x[12];
            if (interior) {
                const float4* rp = (const float4*)(row + lb - 4);
                float4 w0 = rp[0], w1 = rp[1], w2 = rp[2];
                x[0]=w0.x; x[1]=w0.y; x[2]=w0.z; x[3]=w0.w;
                x[4]=w1.x; x[5]=w1.y; x[6]=w1.z; x[7]=w1.w;
                x[8]=w2.x; x[9]=w2.y; x[10]=w2.z; x[11]=w2.w;
            } else {
                #pragma unroll
                for (int w = 0; w < 12; ++w) {
                    int p = l0 + lb - 4 + w;
                    x[w] = (p >= 0 && p < L_) ? row[lb - 4 + w] : 0.f;
                }
            }
            #pragma unroll
            for (int dl = 0; dl < 4; ++dl) {
                float a = 0.f;
                #pragma unroll
                for (int j = 0; j < K_; ++j) a += wr[di][j] * x[dl + 1 + j];
                hv[dl][di] = f2bf(a);
            }
        }
        #pragma unroll
        for (int dl = 0; dl < 4; ++dl) {
            int n = lb + dl;
            u32 lo = (u32)hv[dl][0] | ((u32)hv[dl][1] << 16);
            u32 hi = (u32)hv[dl][2] | ((u32)hv[dl][3] << 16);
            *(uint2*)(&Xs[n * LDK + i0]) = make_uint2(lo, hi);
        }
    }
    __syncthreads();

    f32x4 acc[4][4];
    #pragma unroll
    for (int r = 0; r < 4; ++r)
        #pragma unroll
        for (int c = 0; c < 4; ++c)
            acc[r][c] = (f32x4){0.f, 0.f, 0.f, 0.f};

    const u16* Wrow = Wb + (size_t)(b * O_ + wv * 64 + mlane) * I_;

    for (int kb = 0; kb < 8; ++kb) {
        const int koff = kb * 32 + quad * 8;
        short8 a[4], bbf[4];
        #pragma unroll
        for (int r = 0; r < 4; ++r)
            a[r] = *(const short8*)(Wrow + r * 16 * I_ + koff);
        #pragma unroll
        for (int c = 0; c < 4; ++c)
            bbf[c] = *(const short8*)(&Xs[(c * 16 + mlane) * LDK + koff]);
        #pragma unroll
        for (int r = 0; r < 4; ++r)
            #pragma unroll
            for (int c = 0; c < 4; ++c)
                acc[r][c] = __builtin_amdgcn_mfma_f32_16x16x32_bf16(a[r], bbf[c], acc[r][c], 0, 0, 0);
    }

    float* outb = out + (size_t)b * O_ * L_;
    #pragma unroll
    for (int r = 0; r < 4; ++r) {
        const int obase = wv * 64 + r * 16 + quad * 4;
        #pragma unroll
        for (int p = 0; p < 4; ++p) {
            const int o = obase + p;
            const float bias = proj_b[o];
            float* orow = outb + (size_t)o * L_ + l0 + mlane;
            #pragma unroll
            for (int c = 0; c < 4; ++c)
                orow[c * 16] = acc[r][c][p] + bias;
        }
    }
}

extern "C" void kernel_launch(void* const* d_in, const int* in_sizes, int n_in,
                              void* d_out, int out_size, void* d_ws, size_t ws_size,
                              hipStream_t stream) {
    const float* bx     = (const float*)d_in[0];
    const float* t      = (const float*)d_in[1];
    const float* conv_w = (const float*)d_in[2];
    const float* proj_w = (const float*)d_in[3];
    const float* proj_b = (const float*)d_in[4];
    const float* mod_w  = (const float*)d_in[5];
    const float* mod_b  = (const float*)d_in[6];
    float* out = (float*)d_out;

    // workspace layout (R2 bugfix: Wb is B*O*I bf16 = 2 MB, NOT 256 KB — xt must start after it)
    const size_t OFF_WB = 16384;                                   // mod: 16 KB
    const size_t OFF_XT = OFF_WB + (size_t)B_ * O_ * I_ * 2ull;    // Wb: 2 MB
    const size_t need   = OFF_XT + (size_t)B_ * NTILE * BN * I_ * 2ull;  // xt: 64 MB

    float* mod = (float*)d_ws;
    u16*   Wb  = (u16*)((char*)d_ws + OFF_WB);
    u16*   xt  = (u16*)((char*)d_ws + OFF_XT);

    mod_kernel<<<dim3(16, 16), 256, 0, stream>>>(t, mod_w, mod_b, mod);
    wmod_kernel<<<dim3(16, 16), 256, 0, stream>>>(proj_w, mod, Wb);
    if (ws_size >= need) {
        conv_kernel<<<dim3(NTILE, 16), 256, 0, stream>>>(bx, conv_w, xt);
        gemm_kernel<<<dim3(NTILE, 16), 256, 0, stream>>>(xt, Wb, proj_b, out);
    } else {
        main_kernel<<<dim3(NTILE, 16), 256, 0, stream>>>(bx, conv_w, Wb, proj_b, out);
    }
}

// Round 4
// 316.410 us; speedup vs baseline: 1.1577x; 1.1577x over previous
//
#include <hip/hip_runtime.h>
#include <hip/hip_bf16.h>

#define B_ 16
#define I_ 256
#define O_ 256
#define T_ 512
#define L_ 8192
#define K_ 7
#define CT 1024     // conv l-tile per block
#define NT 128      // number of 64-wide l tiles

typedef unsigned short u16;
typedef unsigned int u32;
typedef __attribute__((ext_vector_type(8))) short short8;
typedef __attribute__((ext_vector_type(4))) float f32x4;

__device__ inline u16 f2bf(float f) {
    union { float f; u32 u; } v; v.f = f;
    u32 r = v.u + 0x7FFF + ((v.u >> 16) & 1);   // RNE
    return (u16)(r >> 16);
}

// Frag-linear layouts (all gemm loads become contiguous 1KB wave-loads):
//   Wsw[b][wv(4)][kb(8)][r(4)][lane(64)][8] u16   -- A-frag for o=wv*64+r*16+(lane&15), i=kb*32+(lane>>4)*8+e
//   Xsw[b][tile(128)][kb(8)][c(4)][lane(64)][8]   -- B-frag for l=tile*64+c*16+(lane&15), i=kb*32+(lane>>4)*8+e

// ---------------- Kernel 1: fused mod + weight-modulation, swizzled output ----------------
// one block per batch; thread tid = channel i (phase 1) then = output o (phase 2).
__global__ __launch_bounds__(256) void wmod_kernel(
    const float* __restrict__ t, const float* __restrict__ mod_w, const float* __restrict__ mod_b,
    const float* __restrict__ proj_w, u16* __restrict__ Wsw)
{
    __shared__ __align__(16) float mod_s[I_];
    const int b = blockIdx.x, tid = threadIdx.x;

    // phase 1: mod[i=tid] = t[b,:] . mod_w[tid,:] + mod_b[tid]
    const float* tb = t + b * T_;
    const float* wr = mod_w + (size_t)tid * T_;
    float s = 0.f;
    #pragma unroll 8
    for (int k = 0; k < T_ / 4; ++k) {
        float4 w4 = *(const float4*)(wr + 4 * k);
        float4 t4 = *(const float4*)(tb + 4 * k);
        s += w4.x * t4.x + w4.y * t4.y + w4.z * t4.z + w4.w * t4.w;
    }
    mod_s[tid] = s + mod_b[tid];
    __syncthreads();

    // phase 2: o = tid. pass 1: sum of squares; pass 2: scale + pack + swizzled store.
    const float* pw = proj_w + (size_t)tid * I_;
    float ss = 0.f;
    #pragma unroll 8
    for (int k = 0; k < I_ / 4; ++k) {
        float4 p = *(const float4*)(pw + 4 * k);
        float4 m = *(const float4*)(&mod_s[4 * k]);
        float a0 = p.x * (m.x + 1.f), a1 = p.y * (m.y + 1.f);
        float a2 = p.z * (m.z + 1.f), a3 = p.w * (m.w + 1.f);
        ss += a0 * a0 + a1 * a1 + a2 * a2 + a3 * a3;
    }
    const float dem = rsqrtf(ss + 1e-8f);
    const int wv = tid >> 6, r = (tid >> 4) & 3, ml = tid & 15;
    #pragma unroll 4
    for (int oc = 0; oc < 32; ++oc) {
        float4 p0 = *(const float4*)(pw + oc * 8);
        float4 p1 = *(const float4*)(pw + oc * 8 + 4);
        float4 m0 = *(const float4*)(&mod_s[oc * 8]);
        float4 m1 = *(const float4*)(&mod_s[oc * 8 + 4]);
        u32 q0 = (u32)f2bf(p0.x * (m0.x + 1.f) * dem) | ((u32)f2bf(p0.y * (m0.y + 1.f) * dem) << 16);
        u32 q1 = (u32)f2bf(p0.z * (m0.z + 1.f) * dem) | ((u32)f2bf(p0.w * (m0.w + 1.f) * dem) << 16);
        u32 q2 = (u32)f2bf(p1.x * (m1.x + 1.f) * dem) | ((u32)f2bf(p1.y * (m1.y + 1.f) * dem) << 16);
        u32 q3 = (u32)f2bf(p1.z * (m1.z + 1.f) * dem) | ((u32)f2bf(p1.w * (m1.w + 1.f) * dem) << 16);
        const int kb = oc >> 2, quad = oc & 3;
        u16* dst = Wsw + ((((size_t)(b * 4 + wv) * 8 + kb) * 4 + r) * 64 + quad * 16 + ml) * 8;
        *(uint4*)dst = make_uint4(q0, q1, q2, q3);   // 16 lanes of ml => 256B contiguous runs
    }
}

// ---------------- Kernel 2: depthwise conv -> frag-linear bf16 ----------------
// block = (ch-octet, 1024-l group, b). Thread owns 8 ch x 4 consecutive l.
// Loads: 3 float4/ch, wave-contiguous 1KB (lane overlap hits L1). Stores via LDS, 256B runs.
__global__ __launch_bounds__(256) void conv_kernel(
    const float* __restrict__ bx, const float* __restrict__ conv_w, u16* __restrict__ Xsw)
{
    __shared__ __align__(16) u16 Os[CT * 8];   // [l_loc][8ch] bf16 chunks, 16 KB
    const int oct = blockIdx.x;    // 0..31
    const int lg  = blockIdx.y;    // 0..7
    const int b   = blockIdx.z;    // 0..15
    const int tid = threadIdx.x;
    const int l0  = lg * CT;
    const int lt  = l0 + tid * 4;
    const float* base = bx + ((size_t)b * I_ + oct * 8) * L_;

    float w[8][K_];                // uniform per block -> scalar loads
    #pragma unroll
    for (int ch = 0; ch < 8; ++ch)
        #pragma unroll
        for (int j = 0; j < K_; ++j)
            w[ch][j] = conv_w[(oct * 8 + ch) * K_ + j];

    const bool okL = (lt > 0);
    const bool okR = (lt + 4 < L_);
    u32 pk[4][4] = {};             // [dl][ch>>1]

    #pragma unroll
    for (int ch = 0; ch < 8; ++ch) {
        const float* row = base + (size_t)ch * L_;
        float4 za = okL ? *(const float4*)(row + lt - 4) : make_float4(0.f, 0.f, 0.f, 0.f);
        float4 zb = *(const float4*)(row + lt);
        float4 zc = okR ? *(const float4*)(row + lt + 4) : make_float4(0.f, 0.f, 0.f, 0.f);
        float x[12] = {za.x, za.y, za.z, za.w, zb.x, zb.y, zb.z, zb.w, zc.x, zc.y, zc.z, zc.w};
        #pragma unroll
        for (int dl = 0; dl < 4; ++dl) {
            float a = 0.f;
            #pragma unroll
            for (int j = 0; j < K_; ++j) a += w[ch][j] * x[dl + 1 + j];
            pk[dl][ch >> 1] |= ((u32)f2bf(a)) << (16 * (ch & 1));
        }
    }
    #pragma unroll
    for (int dl = 0; dl < 4; ++dl)
        *(uint4*)(&Os[(size_t)(tid * 4 + dl) * 8]) = make_uint4(pk[dl][0], pk[dl][1], pk[dl][2], pk[dl][3]);
    __syncthreads();

    const int kb = oct >> 2, quad = oct & 3;
    #pragma unroll
    for (int pass = 0; pass < 4; ++pass) {
        int idx = pass * 256 + tid;
        int l = l0 + idx;
        int tile = l >> 6, c = (l >> 4) & 3, ml = l & 15;
        uint4 v = *(const uint4*)(&Os[(size_t)idx * 8]);
        u16* dst = Xsw + ((((size_t)(b * NT + tile) * 8 + kb) * 4 + c) * 64 + quad * 16 + ml) * 8;
        *(uint4*)dst = v;          // consecutive tid -> consecutive ml -> 256B runs
    }
}

// ---------------- Kernel 3: batched GEMM, frag-linear loads, LDS-staged epilogue ----------------
__global__ __launch_bounds__(256) void gemm_kernel(
    const u16* __restrict__ Xsw, const u16* __restrict__ Wsw,
    const float* __restrict__ proj_b, float* __restrict__ out)
{
    __shared__ __align__(16) float Cs[64 * 68];   // 68 = 64+4 pad: quads split banks
    const int tile = blockIdx.x, b = blockIdx.y;
    const int tid = threadIdx.x, lane = tid & 63, wv = tid >> 6;
    const int ml = lane & 15, quad = lane >> 4;
    const int l0 = tile * 64;

    const u16* Ab = Wsw + ((size_t)(b * 4 + wv) * 8 * 4 * 64) * 8 + (size_t)lane * 8;
    const u16* Bb = Xsw + ((size_t)(b * NT + tile) * 8 * 4 * 64) * 8 + (size_t)lane * 8;

    f32x4 acc[4][4];
    #pragma unroll
    for (int r = 0; r < 4; ++r)
        #pragma unroll
        for (int c = 0; c < 4; ++c)
            acc[r][c] = (f32x4){0.f, 0.f, 0.f, 0.f};

    short8 a[2][4], bb[2][4];
    #pragma unroll
    for (int r = 0; r < 4; ++r) a[0][r] = *(const short8*)(Ab + (size_t)r * 512);
    #pragma unroll
    for (int c = 0; c < 4; ++c) bb[0][c] = *(const short8*)(Bb + (size_t)c * 512);

    #pragma unroll
    for (int kb = 0; kb < 8; ++kb) {
        const int cur = kb & 1, nxt = cur ^ 1;
        if (kb < 7) {
            #pragma unroll
            for (int r = 0; r < 4; ++r) a[nxt][r] = *(const short8*)(Ab + (size_t)((kb + 1) * 4 + r) * 512);
            #pragma unroll
            for (int c = 0; c < 4; ++c) bb[nxt][c] = *(const short8*)(Bb + (size_t)((kb + 1) * 4 + c) * 512);
        }
        #pragma unroll
        for (int r = 0; r < 4; ++r)
            #pragma unroll
            for (int c = 0; c < 4; ++c)
                acc[r][c] = __builtin_amdgcn_mfma_f32_16x16x32_bf16(a[cur][r], bb[cur][c], acc[r][c], 0, 0, 0);
    }

    // epilogue: 4 rounds through LDS; stores are float4 in 256B row-segments
    #pragma unroll
    for (int r = 0; r < 4; ++r) {
        float4 pb = *(const float4*)(proj_b + wv * 64 + r * 16 + quad * 4);
        float pbv[4] = {pb.x, pb.y, pb.z, pb.w};
        #pragma unroll
        for (int c = 0; c < 4; ++c)
            #pragma unroll
            for (int p = 0; p < 4; ++p)
                Cs[(wv * 16 + quad * 4 + p) * 68 + c * 16 + ml] = acc[r][c][p] + pbv[p];
        __syncthreads();
        #pragma unroll
        for (int q = 0; q < 4; ++q) {
            int g = q * 256 + tid;
            int orow = g >> 4, lq = g & 15;
            float4 v = *(const float4*)(&Cs[orow * 68 + lq * 4]);
            int o = (orow >> 4) * 64 + r * 16 + (orow & 15);
            *(float4*)(out + ((size_t)b * O_ + o) * L_ + l0 + lq * 4) = v;
        }
        __syncthreads();
    }
}

extern "C" void kernel_launch(void* const* d_in, const int* in_sizes, int n_in,
                              void* d_out, int out_size, void* d_ws, size_t ws_size,
                              hipStream_t stream) {
    const float* bx     = (const float*)d_in[0];
    const float* t      = (const float*)d_in[1];
    const float* conv_w = (const float*)d_in[2];
    const float* proj_w = (const float*)d_in[3];
    const float* proj_b = (const float*)d_in[4];
    const float* mod_w  = (const float*)d_in[5];
    const float* mod_b  = (const float*)d_in[6];
    float* out = (float*)d_out;

    // ws layout: Wsw 2 MB | Xsw 64 MB  (total 69,206,016 B; proven available in R3)
    u16* Wsw = (u16*)d_ws;
    u16* Xsw = (u16*)((char*)d_ws + (size_t)B_ * 4 * 8 * 4 * 64 * 8 * 2);

    wmod_kernel<<<dim3(B_), 256, 0, stream>>>(t, mod_w, mod_b, proj_w, Wsw);
    conv_kernel<<<dim3(32, L_ / CT, B_), 256, 0, stream>>>(bx, conv_w, Xsw);
    gemm_kernel<<<dim3(NT, B_), 256, 0, stream>>>(Xsw, Wsw, proj_b, out);
}